// Round 3
// baseline (2223.688 us; speedup 1.0000x reference)
//
#include <hip/hip_runtime.h>

// trajectory2seq round 3.
// enc_kernel: 128 blocks x 640 thr (10 waves), launch_bounds(640,3) so xr[64]
//   stays in VGPRs (round-2 VGPR=56 showed the compiler spilled x to LDS reads).
//   No x LDS tile: each lane loads its own 256B x-row (16x global f4, 4 lines).
//   Wave w owns hidden units {w, w+10} for both layers; layer1 pipelined one
//   step behind layer0 -> one barrier/iteration. h-state transposed+dbuf in LDS.
// dec_kernel: 128 blocks x 1024 thr (16 waves, 4/SIMD), 64 batch lanes,
//   round-1 structure (wave-uniform weights -> s_load, 256B coalesced enc reads),
//   LDS overlaid into exactly 64.0 KB.
// ws: enc [128][20][8192] fp32 + hf0/hf1 [8192][20] fp32 (87.6 MB).

#define HN 20
#define DIN 64
#define NVOCAB 128
#define NB 8192
#define NS 128
#define NDEC 6

#define HID_OFF (NB * NDEC * NVOCAB)      // 6291456
#define ATTN_OFF (HID_OFF + 2 * NB * HN)  // 6619136

__device__ __forceinline__ float sigf(float x) {
    return 1.0f / (1.0f + __expf(-x));
}
__device__ __forceinline__ float tanh_fast(float x) {
    return 1.0f - 2.0f / (1.0f + __expf(2.0f * x));
}

__global__ __launch_bounds__(640, 3)
void enc_kernel(const float* __restrict__ x,
                const float* __restrict__ Wih0, const float* __restrict__ Whh0,
                const float* __restrict__ bih0, const float* __restrict__ bhh0,
                const float* __restrict__ Wih1, const float* __restrict__ Whh1,
                const float* __restrict__ bih1, const float* __restrict__ bhh1,
                float* __restrict__ enc, float* __restrict__ hf0,
                float* __restrict__ hf1)
{
    __shared__ float h0s[2][HN][64];     // transposed [k][b], double-buffered
    __shared__ float h1s[2][HN][64];

    const int tid = threadIdx.x;
    const int l   = tid & 63;
    const int w   = __builtin_amdgcn_readfirstlane(tid >> 6);  // 0..9
    const int b0  = blockIdx.x * 64;
    const int b   = b0 + l;
    const int k0  = w;
    const int k1  = w + 10;

    for (int i = tid; i < 2 * HN * 64; i += 640) {
        (&h0s[0][0][0])[i] = 0.0f;
        (&h1s[0][0][0])[i] = 0.0f;
    }
    __syncthreads();

    const float* xrow = x + (size_t)b * (NS * DIN);

    int p = 0;
    for (int u = 0; u <= NS; ++u) {
        const int q = p ^ 1;

        // h0 state entering step u (= h0^{(u-1)}), also layer-1 input
        float h0r[HN];
        #pragma unroll
        for (int i = 0; i < HN; ++i) h0r[i] = h0s[p][i][l];

        if (u < NS) {
            // ---- layer 0: per-lane x row straight from global (4 cache lines) ----
            float xr[DIN];
            {
                const float4* xv = (const float4*)(xrow + (size_t)u * DIN);
                #pragma unroll
                for (int qq = 0; qq < 16; ++qq) {
                    float4 v = xv[qq];
                    xr[4*qq] = v.x; xr[4*qq+1] = v.y; xr[4*qq+2] = v.z; xr[4*qq+3] = v.w;
                }
            }
            #pragma unroll
            for (int c = 0; c < 2; ++c) {
                const int kk = (c == 0) ? k0 : k1;
                float ar = bih0[kk], az = bih0[20 + kk], an = bih0[40 + kk];
                #pragma unroll
                for (int i = 0; i < DIN; ++i) {
                    ar += Wih0[kk * DIN + i] * xr[i];
                    az += Wih0[(20 + kk) * DIN + i] * xr[i];
                    an += Wih0[(40 + kk) * DIN + i] * xr[i];
                }
                float hr = bhh0[kk], hz = bhh0[20 + kk], hn = bhh0[40 + kk];
                #pragma unroll
                for (int i = 0; i < HN; ++i) {
                    hr += Whh0[kk * HN + i] * h0r[i];
                    hz += Whh0[(20 + kk) * HN + i] * h0r[i];
                    hn += Whh0[(40 + kk) * HN + i] * h0r[i];
                }
                float rr = sigf(ar + hr);
                float zz = sigf(az + hz);
                float nn = tanh_fast(an + rr * hn);
                float hnew = (1.0f - zz) * nn + zz * h0r[kk];
                h0s[q][kk][l] = hnew;
                if (u == NS - 1) hf0[(size_t)b * HN + kk] = hnew;
            }
        }

        if (u >= 1) {
            // ---- layer 1 at step u-1: input h0^{(u-1)} = h0r ----
            float h1r[HN];
            #pragma unroll
            for (int i = 0; i < HN; ++i) h1r[i] = h1s[p][i][l];
            #pragma unroll
            for (int c = 0; c < 2; ++c) {
                const int kk = (c == 0) ? k0 : k1;
                float ar = bih1[kk], az = bih1[20 + kk], an = bih1[40 + kk];
                float hr = bhh1[kk], hz = bhh1[20 + kk], hn = bhh1[40 + kk];
                #pragma unroll
                for (int i = 0; i < HN; ++i) {
                    ar += Wih1[kk * HN + i] * h0r[i];
                    az += Wih1[(20 + kk) * HN + i] * h0r[i];
                    an += Wih1[(40 + kk) * HN + i] * h0r[i];
                    hr += Whh1[kk * HN + i] * h1r[i];
                    hz += Whh1[(20 + kk) * HN + i] * h1r[i];
                    hn += Whh1[(40 + kk) * HN + i] * h1r[i];
                }
                float rr = sigf(ar + hr);
                float zz = sigf(az + hz);
                float nn = tanh_fast(an + rr * hn);
                float hnew = (1.0f - zz) * nn + zz * h1r[kk];
                h1s[q][kk][l] = hnew;
                enc[((size_t)(u - 1) * HN + kk) * NB + b] = hnew;
                if (u == NS) hf1[(size_t)b * HN + kk] = hnew;
            }
        }
        __syncthreads();
        p = q;
    }
}

__global__ __launch_bounds__(1024, 4)
void dec_kernel(const float* __restrict__ dWih0, const float* __restrict__ dWhh0,
                const float* __restrict__ dbih0, const float* __restrict__ dbhh0,
                const float* __restrict__ dWih1, const float* __restrict__ dWhh1,
                const float* __restrict__ dbih1, const float* __restrict__ dbhh1,
                const float* __restrict__ emb,  const float* __restrict__ qW,
                const float* __restrict__ qb,   const float* __restrict__ combW,
                const float* __restrict__ combb, const float* __restrict__ outW,
                const float* __restrict__ outb,
                const float* __restrict__ enc, const float* __restrict__ hf0,
                const float* __restrict__ hf1, float* __restrict__ out)
{
    // 64.0 KB total: uA is shared by GRU gates (cols 0..80), attn (0..127),
    // logits (0..127) with barriers between the phases.
    __shared__ float hd0[64][21], hd1[64][21];   // 10752 B
    __shared__ float uA[64][130];                // 33280 B
    __shared__ float bufB[64][43];               // 11008 B  (emb/q/ctx 0..19, comb 21..40)
    __shared__ float redM[64][17];               // 4352 B   (also lmax)
    __shared__ float redS[64][17];               // 4352 B   (also lidx via cast)
    __shared__ int   toks[64];                   // 256 B
    float (*lmax)[17] = redM;
    int   (*lidx)[17] = (int (*)[17])redS;

    const int tid = threadIdx.x;
    const int l   = tid & 63;
    const int w   = __builtin_amdgcn_readfirstlane(tid >> 6);  // 0..15
    const int b0  = blockIdx.x * 64;
    const int b   = b0 + l;

    for (int idx = tid; idx < 64 * HN; idx += 1024) {
        int e = idx / HN, k = idx % HN;
        hd0[e][k] = hf0[(size_t)b0 * HN + idx];
        hd1[e][k] = hf1[(size_t)b0 * HN + idx];
    }
    if (tid < 64) toks[tid] = 0;
    __syncthreads();

    for (int s = 0; s < NDEC; ++s) {
        // ---- embedding ----
        for (int k = w; k < HN; k += 16) bufB[l][k] = emb[toks[l] * HN + k];
        __syncthreads();

        // ---- GRU layer 0 (input = embedding) ----
        {
            float er[HN], hr[HN];
            #pragma unroll
            for (int i = 0; i < HN; ++i) { er[i] = bufB[l][i]; hr[i] = hd0[l][i]; }
            for (int j = w; j < 60; j += 16) {
                float ax = dbih0[j], ah = dbhh0[j];
                #pragma unroll
                for (int i = 0; i < HN; ++i) ax += dWih0[j * HN + i] * er[i];
                #pragma unroll
                for (int i = 0; i < HN; ++i) ah += dWhh0[j * HN + i] * hr[i];
                if (j < 40) uA[l][j] = ax + ah;
                else { uA[l][j] = ax; uA[l][j + 20] = ah; }
            }
        }
        __syncthreads();
        for (int k = w; k < HN; k += 16) {
            float r = sigf(uA[l][k]);
            float z = sigf(uA[l][20 + k]);
            float n = tanh_fast(uA[l][40 + k] + r * uA[l][60 + k]);
            hd0[l][k] = (1.0f - z) * n + z * hd0[l][k];
        }
        __syncthreads();

        // ---- GRU layer 1 (input = hd0 new) ----
        {
            float er[HN], hr[HN];
            #pragma unroll
            for (int i = 0; i < HN; ++i) { er[i] = hd0[l][i]; hr[i] = hd1[l][i]; }
            for (int j = w; j < 60; j += 16) {
                float ax = dbih1[j], ah = dbhh1[j];
                #pragma unroll
                for (int i = 0; i < HN; ++i) ax += dWih1[j * HN + i] * er[i];
                #pragma unroll
                for (int i = 0; i < HN; ++i) ah += dWhh1[j * HN + i] * hr[i];
                if (j < 40) uA[l][j] = ax + ah;
                else { uA[l][j] = ax; uA[l][j + 20] = ah; }
            }
        }
        __syncthreads();
        for (int k = w; k < HN; k += 16) {
            float r = sigf(uA[l][k]);
            float z = sigf(uA[l][20 + k]);
            float n = tanh_fast(uA[l][40 + k] + r * uA[l][60 + k]);
            hd1[l][k] = (1.0f - z) * n + z * hd1[l][k];
        }
        __syncthreads();

        float h1r[HN];
        #pragma unroll
        for (int i = 0; i < HN; ++i) h1r[i] = hd1[l][i];

        // ---- query (overwrites embedding region of bufB) ----
        for (int k = w; k < HN; k += 16) {
            float a = qb[k];
            #pragma unroll
            for (int i = 0; i < HN; ++i) a += qW[k * HN + i] * h1r[i];
            bufB[l][k] = a;
        }
        __syncthreads();

        // ---- scores + softmax: wave w owns t in [8w, 8w+8) ----
        {
            float qr[HN];
            #pragma unroll
            for (int i = 0; i < HN; ++i) qr[i] = bufB[l][i];
            const int t0 = w * 8;
            float sreg[8];
            float mx = -1e30f;
            #pragma unroll
            for (int u = 0; u < 8; ++u) {
                int t = t0 + u;
                float a = 0.0f;
                #pragma unroll
                for (int k = 0; k < HN; ++k)
                    a += qr[k] * enc[((size_t)t * HN + k) * NB + b];
                sreg[u] = a;
                mx = fmaxf(mx, a);
            }
            redM[l][w] = mx;
            __syncthreads();
            float M = redM[l][0];
            #pragma unroll
            for (int j = 1; j < 16; ++j) M = fmaxf(M, redM[l][j]);
            float ssum = 0.0f;
            #pragma unroll
            for (int u = 0; u < 8; ++u) {
                float e = __expf(sreg[u] - M);
                sreg[u] = e;
                ssum += e;
            }
            redS[l][w] = ssum;
            __syncthreads();
            float S = 0.0f;
            #pragma unroll
            for (int j = 0; j < 16; ++j) S += redS[l][j];
            float inv = 1.0f / S;
            #pragma unroll
            for (int u = 0; u < 8; ++u) uA[l][t0 + u] = sreg[u] * inv;
        }
        __syncthreads();

        // ---- attention-weight output (coalesced) ----
        for (int it = 0; it < 8; ++it) {
            int idx = it * 1024 + tid;
            int e = idx >> 7, tt = idx & 127;
            out[ATTN_OFF + (size_t)s * NB * NS + (size_t)(b0 + e) * NS + tt] = uA[e][tt];
        }

        // ---- context: wave w owns k (waves 0..3 also k=w+16) ----
        for (int k = w; k < HN; k += 16) {
            float acc = 0.0f;
            for (int t = 0; t < NS; ++t)
                acc += uA[l][t] * enc[((size_t)t * HN + k) * NB + b];
            bufB[l][k] = acc;   // query dead; safe after the barrier above
        }
        __syncthreads();

        // ---- comb = [buf, ctx] @ comb_W.T + comb_b ----
        {
            float cr[HN];
            #pragma unroll
            for (int i = 0; i < HN; ++i) cr[i] = bufB[l][i];
            for (int k = w; k < HN; k += 16) {
                float a = combb[k];
                #pragma unroll
                for (int i = 0; i < HN; ++i) a += combW[k * 2 * HN + i] * h1r[i];
                #pragma unroll
                for (int i = 0; i < HN; ++i) a += combW[k * 2 * HN + HN + i] * cr[i];
                bufB[l][21 + k] = a;
            }
        }
        __syncthreads();

        // ---- logits + per-wave argmax: wave w owns v in [8w, 8w+8) ----
        {
            float cr[HN];
            #pragma unroll
            for (int i = 0; i < HN; ++i) cr[i] = bufB[l][21 + i];
            float best = -1e30f; int bi = 0;
            #pragma unroll
            for (int u = 0; u < 8; ++u) {
                int v = w * 8 + u;
                float a = outb[v];
                #pragma unroll
                for (int k = 0; k < HN; ++k) a += outW[v * HN + k] * cr[k];
                uA[l][v] = a;       // attn region dead after context barrier
                if (a > best) { best = a; bi = v; }   // strict >: first index wins
            }
            lmax[l][w] = best;
            lidx[l][w] = bi;
        }
        __syncthreads();

        // ---- logits write (coalesced) + argmax combine ----
        for (int it = 0; it < 8; ++it) {
            int idx = it * 1024 + tid;
            int e = idx >> 7, v = idx & 127;
            out[(size_t)(b0 + e) * (NDEC * NVOCAB) + s * NVOCAB + v] = uA[e][v];
        }
        if (tid < 64) {
            float bb = lmax[tid][0]; int ii = lidx[tid][0];
            #pragma unroll
            for (int j = 1; j < 16; ++j)
                if (lmax[tid][j] > bb) { bb = lmax[tid][j]; ii = lidx[tid][j]; }
            toks[tid] = ii;
        }
        __syncthreads();
    }

    // ---- final hidden state [2][B][H] ----
    for (int idx = tid; idx < 64 * HN; idx += 1024) {
        int e = idx / HN, k = idx % HN;
        out[HID_OFF + (size_t)b0 * HN + idx] = hd0[e][k];
        out[HID_OFF + (size_t)NB * HN + (size_t)b0 * HN + idx] = hd1[e][k];
    }
}

extern "C" void kernel_launch(void* const* d_in, const int* in_sizes, int n_in,
                              void* d_out, int out_size, void* d_ws, size_t ws_size,
                              hipStream_t stream)
{
    const float* x     = (const float*)d_in[0];
    const float* eWih0 = (const float*)d_in[1];
    const float* eWhh0 = (const float*)d_in[2];
    const float* ebih0 = (const float*)d_in[3];
    const float* ebhh0 = (const float*)d_in[4];
    const float* eWih1 = (const float*)d_in[5];
    const float* eWhh1 = (const float*)d_in[6];
    const float* ebih1 = (const float*)d_in[7];
    const float* ebhh1 = (const float*)d_in[8];
    const float* dWih0 = (const float*)d_in[9];
    const float* dWhh0 = (const float*)d_in[10];
    const float* dbih0 = (const float*)d_in[11];
    const float* dbhh0 = (const float*)d_in[12];
    const float* dWih1 = (const float*)d_in[13];
    const float* dWhh1 = (const float*)d_in[14];
    const float* dbih1 = (const float*)d_in[15];
    const float* dbhh1 = (const float*)d_in[16];
    const float* emb   = (const float*)d_in[17];
    const float* qW    = (const float*)d_in[18];
    const float* qb    = (const float*)d_in[19];
    const float* combW = (const float*)d_in[20];
    const float* combb = (const float*)d_in[21];
    const float* outW  = (const float*)d_in[22];
    const float* outb  = (const float*)d_in[23];

    const size_t need = ((size_t)NS * HN * NB + 2 * (size_t)NB * HN) * sizeof(float);
    if (ws_size < need) return;

    float* ws  = (float*)d_ws;
    float* enc = ws;
    float* hf0 = ws + (size_t)NS * HN * NB;
    float* hf1 = hf0 + (size_t)NB * HN;

    enc_kernel<<<128, 640, 0, stream>>>(x, eWih0, eWhh0, ebih0, ebhh0,
                                        eWih1, eWhh1, ebih1, ebhh1,
                                        enc, hf0, hf1);
    dec_kernel<<<128, 1024, 0, stream>>>(dWih0, dWhh0, dbih0, dbhh0,
                                         dWih1, dWhh1, dbih1, dbhh1,
                                         emb, qW, qb, combW, combb, outW, outb,
                                         enc, hf0, hf1, (float*)d_out);
}